// Round 3
// baseline (390.854 us; speedup 1.0000x reference)
//
#include <hip/hip_runtime.h>

// ---------------------------------------------------------------------------
// HOI top-k, R=262144 x K=117, topk=100, thresh=0.05
//
//  K1 k_main   : full streaming pass. Quick-reject hoi<=0.75 (bs<1 => s<=hoi).
//                LDS window histogram (80 bins, s>0.75) flushed into 32
//                replicated global histograms (kills same-line atomic drain).
//                Candidates >= 0.898 collected to a global buffer. The LAST
//                block (atomic done-counter) reduces replicas, finds exact
//                cutoff bin T, filters+bitonic-sorts candidates in LDS
//                (value desc, index asc = stable top_k order), writes output.
//  K2 k_safety : 1 block; early-exits unless k_main flagged slow path.
//                Exact full recompute (576-bin hist) — correctness net.
// ---------------------------------------------------------------------------

#define NB        576          // full histogram bins (top-16 float bits - base)
#define BIN_BASE  15692        // (bits of 0.05f) >> 16
#define WLO       500          // window start: bin of 0.75f (0x3F40)
#define WN        80           // window bins (576-500=76, padded)
#define VLO       0.75f        // value at bin WLO
#define G_REL     538          // bin of 0.8984375 -> opportunistic collect
#define FCAP      2048         // sort capacity (power of 2), 16 KiB LDS
#define NREP      32           // histogram replicas
#define REPS      96           // replica stride (ints)
#define THRESH    0.05f
#define NEG_INF   __int_as_float(0xFF800000)

__device__ __forceinline__ int bin_of(float s) {
  // valid only for s > 0 (positive floats: bit order == value order)
  int b = (int)(__float_as_uint(s) >> 16) - BIN_BASE;
  return b > (NB - 1) ? (NB - 1) : b;
}

// ctrl layout (ints): [0]=cand_cnt  [1]=done_counter  [2]=T  [3]=slow_flag

template <int KC>
__global__ __launch_bounds__(256) void k_main(
    const float4* __restrict__ hoi4, const float* __restrict__ ps,
    const float* __restrict__ os, const float4* __restrict__ pbox,
    const float4* __restrict__ obox, const int* __restrict__ ocls,
    int N4, int N, int Kc, int* __restrict__ ctrl, int* __restrict__ rep,
    float* __restrict__ cand_v, int* __restrict__ cand_i, int cap,
    float* __restrict__ out, int topk) {
  __shared__ int lh[WN];
  __shared__ int wh[WN];
  __shared__ float sv[FCAP];
  __shared__ int si[FCAP];
  __shared__ int s_misc[4];    // [0]=amLast [1]=T [2]=cand n [3]=scnt
  if (threadIdx.x < WN) lh[threadIdx.x] = 0;
  __syncthreads();

  const int k = KC ? KC : Kc;
  const int TT = gridDim.x * blockDim.x;
  const int tid = blockIdx.x * blockDim.x + threadIdx.x;

  auto process = [&](int t, const float4& h) {
    float vals[4] = {h.x, h.y, h.z, h.w};
    int i0 = 4 * t;
#pragma unroll
    for (int j = 0; j < 4; ++j) {
      if (vals[j] > VLO) {             // quick reject: bs<1 => s <= hoi
        int i = i0 + j;
        int q = i / k;                 // constant k -> magic mul
        float s = vals[j] * (ps[q] * os[q]);   // = hoi * box_scores (exact ref)
        if (s > VLO) {
          int b = bin_of(s);
          atomicAdd(&lh[b - WLO], 1);
          if (b >= G_REL) {
            int slot = atomicAdd(&ctrl[0], 1);
            if (slot < cap) { cand_v[slot] = s; cand_i[slot] = i; }
          }
        }
      }
    }
  };

  for (int t0 = tid; t0 < N4; t0 += 4 * TT) {
    int t1 = t0 + TT, t2 = t0 + 2 * TT, t3 = t0 + 3 * TT;
    float4 h0 = hoi4[t0];              // 4 independent loads in flight
    float4 h1 = hoi4[t1 < N4 ? t1 : t0];
    float4 h2 = hoi4[t2 < N4 ? t2 : t0];
    float4 h3 = hoi4[t3 < N4 ? t3 : t0];
    process(t0, h0);
    if (t1 < N4) process(t1, h1);
    if (t2 < N4) process(t2, h2);
    if (t3 < N4) process(t3, h3);
  }
  if (blockIdx.x == 0) {               // scalar tail (N % 4)
    const float* hoi = (const float*)hoi4;
    for (int i = N4 * 4 + threadIdx.x; i < N; i += blockDim.x) {
      float v = hoi[i];
      if (v > VLO) {
        int q = i / k;
        float s = v * (ps[q] * os[q]);
        if (s > VLO) {
          int b = bin_of(s);
          atomicAdd(&lh[b - WLO], 1);
          if (b >= G_REL) {
            int slot = atomicAdd(&ctrl[0], 1);
            if (slot < cap) { cand_v[slot] = s; cand_i[slot] = i; }
          }
        }
      }
    }
  }
  __syncthreads();
  if (threadIdx.x < WN) {              // 32-way replicated flush
    int c = lh[threadIdx.x];
    if (c) atomicAdd(&rep[(blockIdx.x & (NREP - 1)) * REPS + threadIdx.x], c);
  }
  __threadfence();                     // release: hist + cand visible
  __syncthreads();
  if (threadIdx.x == 0) {
    int prev = atomicAdd(&ctrl[1], 1);
    s_misc[0] = (prev == (int)gridDim.x - 1) ? 1 : 0;
  }
  __syncthreads();
  if (!s_misc[0]) return;

  // ---------------- finishing block (last to complete) ----------------
  __threadfence();                     // acquire
  if (threadIdx.x < WN) {
    int sum = 0;
#pragma unroll
    for (int r = 0; r < NREP; ++r) sum += rep[r * REPS + threadIdx.x];
    wh[threadIdx.x] = sum;
  }
  __syncthreads();
  if (threadIdx.x == 0) {
    int cum = 0, T = -1;
    for (int b = WN - 1; b >= 0; --b) {
      cum += wh[b];
      if (T < 0 && cum >= topk) T = b + WLO;
    }
    int cnt = ctrl[0];
    int fast = (T >= G_REL && cnt <= cap) ? 1 : 0;
    ctrl[2] = T;
    ctrl[3] = fast ? 0 : 1;
    s_misc[1] = fast ? T : -1;
    s_misc[2] = cnt > cap ? cap : cnt;
    s_misc[3] = 0;
  }
  __syncthreads();
  const int T = s_misc[1];
  if (T < 0) return;                   // slow path -> k_safety
  const int n = s_misc[2];
  for (int t = threadIdx.x; t < n; t += blockDim.x) {
    float v = cand_v[t];
    if (bin_of(v) >= T) {
      int slot = atomicAdd(&s_misc[3], 1);
      if (slot < FCAP) { sv[slot] = v; si[slot] = cand_i[t]; }
    }
  }
  __syncthreads();
  int m = s_misc[3];
  if (m > FCAP) {                      // degenerate -> safety net
    if (threadIdx.x == 0) ctrl[3] = 1;
    return;
  }
  int P = 128;
  while (P < m) P <<= 1;
  for (int t = m + threadIdx.x; t < P; t += blockDim.x) {
    sv[t] = NEG_INF;
    si[t] = 0x7FFFFFFF;
  }
  for (int kk = 2; kk <= P; kk <<= 1) {
    for (int j = kk >> 1; j > 0; j >>= 1) {
      __syncthreads();
      for (int i = threadIdx.x; i < P; i += blockDim.x) {
        int l = i ^ j;
        if (l > i) {
          float vi = sv[i], vl = sv[l];
          int ii = si[i], il = si[l];
          bool before = (vi > vl) || (vi == vl && ii < il);
          if (((i & kk) == 0) != before) {
            sv[i] = vl; sv[l] = vi; si[i] = il; si[l] = ii;
          }
        }
      }
    }
  }
  __syncthreads();
  if ((int)threadIdx.x < topk) {
    int o = threadIdx.x;
    float v = sv[o];
    int idx = si[o];
    bool valid = (idx != 0x7FFFFFFF) && (v > THRESH);
    int safe = valid ? idx : 0;
    int pair = safe / Kc;
    int act = safe - pair * Kc;
    float4 pb = pbox[pair];
    float4 ob = obox[pair];
    out[o] = valid ? v : 0.0f;
    float* pdst = out + topk + 4 * o;
    pdst[0] = pb.x; pdst[1] = pb.y; pdst[2] = pb.z; pdst[3] = pb.w;
    float* odst = out + 5 * topk + 4 * o;
    odst[0] = ob.x; odst[1] = ob.y; odst[2] = ob.z; odst[3] = ob.w;
    out[9 * topk + o] = (float)ocls[pair];
    out[10 * topk + o] = (float)act;
    out[11 * topk + o] = valid ? 1.0f : 0.0f;
  }
}

// Exact fallback; normally exits immediately (ctrl[3]==0).
__global__ __launch_bounds__(1024) void k_safety(
    const float* __restrict__ hoi, const float* __restrict__ ps,
    const float* __restrict__ os, const float4* __restrict__ pbox,
    const float4* __restrict__ obox, const int* __restrict__ ocls,
    int N, int Kc, const int* __restrict__ ctrl, float* __restrict__ out,
    int topk) {
  if (ctrl[3] == 0) return;
  __shared__ int lh[NB];
  __shared__ float sv[FCAP];
  __shared__ int si[FCAP];
  __shared__ int sT, scnt;
  for (int b = threadIdx.x; b < NB; b += blockDim.x) lh[b] = 0;
  if (threadIdx.x == 0) scnt = 0;
  __syncthreads();
  for (int i = threadIdx.x; i < N; i += blockDim.x) {
    int q = i / Kc;
    float s = hoi[i] * (ps[q] * os[q]);
    if (s > THRESH) atomicAdd(&lh[bin_of(s)], 1);
  }
  __syncthreads();
  if (threadIdx.x == 0) {
    int cum = 0, T = 0;
    for (int b = NB - 1; b >= 0; --b) {
      cum += lh[b];
      if (cum >= topk) { T = b; break; }
    }
    sT = T;
  }
  __syncthreads();
  const int T = sT;
  for (int i = threadIdx.x; i < N; i += blockDim.x) {
    int q = i / Kc;
    float s = hoi[i] * (ps[q] * os[q]);
    if (s > THRESH && bin_of(s) >= T) {
      int slot = atomicAdd(&scnt, 1);
      if (slot < FCAP) { sv[slot] = s; si[slot] = i; }
    }
  }
  __syncthreads();
  int m = scnt > FCAP ? FCAP : scnt;
  int P = 128;
  while (P < m) P <<= 1;
  for (int t = m + threadIdx.x; t < P; t += blockDim.x) {
    sv[t] = NEG_INF;
    si[t] = 0x7FFFFFFF;
  }
  for (int kk = 2; kk <= P; kk <<= 1) {
    for (int j = kk >> 1; j > 0; j >>= 1) {
      __syncthreads();
      for (int i = threadIdx.x; i < P; i += blockDim.x) {
        int l = i ^ j;
        if (l > i) {
          float vi = sv[i], vl = sv[l];
          int ii = si[i], il = si[l];
          bool before = (vi > vl) || (vi == vl && ii < il);
          if (((i & kk) == 0) != before) {
            sv[i] = vl; sv[l] = vi; si[i] = il; si[l] = ii;
          }
        }
      }
    }
  }
  __syncthreads();
  if ((int)threadIdx.x < topk) {
    int o = threadIdx.x;
    float v = sv[o];
    int idx = si[o];
    bool valid = (idx != 0x7FFFFFFF) && (v > THRESH);
    int safe = valid ? idx : 0;
    int pair = safe / Kc;
    int act = safe - pair * Kc;
    float4 pb = pbox[pair];
    float4 ob = obox[pair];
    out[o] = valid ? v : 0.0f;
    float* pdst = out + topk + 4 * o;
    pdst[0] = pb.x; pdst[1] = pb.y; pdst[2] = pb.z; pdst[3] = pb.w;
    float* odst = out + 5 * topk + 4 * o;
    odst[0] = ob.x; odst[1] = ob.y; odst[2] = ob.z; odst[3] = ob.w;
    out[9 * topk + o] = (float)ocls[pair];
    out[10 * topk + o] = (float)act;
    out[11 * topk + o] = valid ? 1.0f : 0.0f;
  }
}

extern "C" void kernel_launch(void* const* d_in, const int* in_sizes, int n_in,
                              void* d_out, int out_size, void* d_ws, size_t ws_size,
                              hipStream_t stream) {
  const float* pbox = (const float*)d_in[0];
  const float* obox = (const float*)d_in[1];
  const float* ps   = (const float*)d_in[2];
  const float* os   = (const float*)d_in[3];
  const int*   ocls = (const int*)d_in[4];
  const float* hoi  = (const float*)d_in[5];
  float* out = (float*)d_out;

  const int R    = in_sizes[2];
  const int N    = in_sizes[5];
  const int Kc   = N / R;              // 117
  const int topk = out_size / 12;      // 100

  // ws: ctrl[64 ints] @0 | replicas 32x96 ints @256 | cand_v/cand_i @12544
  int* ctrl = (int*)d_ws;
  int* rep  = (int*)((char*)d_ws + 256);
  float* cand_v = (float*)((char*)d_ws + 12544);
  size_t cand_budget = (ws_size > 12544) ? (ws_size - 12544) / 8 : 1024;
  int cap = cand_budget > 8192 ? 8192 : (int)cand_budget;
  int* cand_i = (int*)((char*)d_ws + 12544 + (size_t)cap * sizeof(float));

  hipMemsetAsync(d_ws, 0, 12544, stream);   // zero ctrl + replicas

  const int N4 = N / 4;
  if (Kc == 117) {
    k_main<117><<<2048, 256, 0, stream>>>(
        (const float4*)hoi, ps, os, (const float4*)pbox, (const float4*)obox,
        ocls, N4, N, Kc, ctrl, rep, cand_v, cand_i, cap, out, topk);
  } else {
    k_main<0><<<2048, 256, 0, stream>>>(
        (const float4*)hoi, ps, os, (const float4*)pbox, (const float4*)obox,
        ocls, N4, N, Kc, ctrl, rep, cand_v, cand_i, cap, out, topk);
  }
  k_safety<<<1, 1024, 0, stream>>>(hoi, ps, os, (const float4*)pbox,
                                   (const float4*)obox, ocls, N, Kc, ctrl,
                                   out, topk);
}